// Round 11
// baseline (197.477 us; speedup 1.0000x reference)
//
#include <hip/hip_runtime.h>
#include <hip/hip_bf16.h>

typedef __attribute__((ext_vector_type(8))) short bf16x8;
typedef __attribute__((ext_vector_type(8))) unsigned short u16x8;
typedef __attribute__((ext_vector_type(4))) float f32x4;

#define D_MODEL 512
#define HEAD_DIM 64
#define N_HEADS 8
#define SEQ 2048

#if __has_builtin(__builtin_amdgcn_exp2f)
#define EXP2(x) __builtin_amdgcn_exp2f(x)
#else
#define EXP2(x) __expf((x) * 0.69314718f)
#endif

__device__ __forceinline__ unsigned short f2bf(float f) {
    unsigned int u = __float_as_uint(f);
    u += 0x7FFFu + ((u >> 16) & 1u);   // round-to-nearest-even
    return (unsigned short)(u >> 16);
}
__device__ __forceinline__ float bf2f(unsigned short h) {
    return __uint_as_float(((unsigned int)h) << 16);
}
// packed f32x2 -> bf16x2 (v_cvt_pk_bf16_f32 on gfx950)
__device__ __forceinline__ unsigned int pkbf(float a, float b) {
    __hip_bfloat162 h2 = __float22bfloat162_rn(make_float2(a, b));
    unsigned int u;
    __builtin_memcpy(&u, &h2, 4);
    return u;
}

// ---------------- cast fp32 -> bf16: x and 4 weight matrices, one launch ----------------
__global__ void cast_all(const float* __restrict__ x, unsigned short* __restrict__ xb,
                         const float* __restrict__ w0, const float* __restrict__ w1,
                         const float* __restrict__ w2, const float* __restrict__ w3,
                         unsigned short* __restrict__ d0, unsigned short* __restrict__ d1,
                         unsigned short* __restrict__ d2, unsigned short* __restrict__ d3,
                         int n8x) {
    int i = blockIdx.x * blockDim.x + threadIdx.x;
    const float* src; unsigned short* dst; int idx;
    if (i < n8x) { src = x; dst = xb; idx = i; }
    else {
        int j = i - n8x;
        int w = j >> 15; idx = j & 32767;
        switch (w) {
            case 0: src = w0; dst = d0; break;
            case 1: src = w1; dst = d1; break;
            case 2: src = w2; dst = d2; break;
            default: src = w3; dst = d3; break;
        }
        if (w > 3) return;
    }
    const float4* s = (const float4*)src;
    float4 a = s[idx * 2], b = s[idx * 2 + 1];
    u16x8 o;
    o[0] = f2bf(a.x); o[1] = f2bf(a.y); o[2] = f2bf(a.z); o[3] = f2bf(a.w);
    o[4] = f2bf(b.x); o[5] = f2bf(b.y); o[6] = f2bf(b.z); o[7] = f2bf(b.w);
    ((u16x8*)dst)[idx] = o;
}

// ---------------- RoPE on Q,K (bf16, in place); Q additionally scaled by SC ----------------
#define SOFTMAX_SC 0.18033688f   // 1/sqrt(64) * log2(e): attn then uses exp2(S) directly
__global__ void rope_kernel(unsigned short* __restrict__ Qb, unsigned short* __restrict__ Kb,
                            const float* __restrict__ qpos, const float* __restrict__ kpos) {
    int row = blockIdx.x;
    int t = threadIdx.x;
    int h = t >> 5, j = t & 31;
    float pq = qpos[row * 2] + qpos[row * 2 + 1];
    float pk = kpos[row * 2] + kpos[row * 2 + 1];
    float invf = __powf(10000.0f, -(float)j * (1.0f / 16.0f));
    float sq, cq, sk, ck;
    sincosf(pq * invf, &sq, &cq);
    sincosf(pk * invf, &sk, &ck);
    size_t idx = (size_t)row * D_MODEL + h * HEAD_DIM + 2 * j;
    float e = bf2f(Qb[idx]), o = bf2f(Qb[idx + 1]);
    Qb[idx]     = f2bf((e * cq - o * sq) * SOFTMAX_SC);
    Qb[idx + 1] = f2bf((e * sq + o * cq) * SOFTMAX_SC);
    e = bf2f(Kb[idx]); o = bf2f(Kb[idx + 1]);
    Kb[idx]     = f2bf(e * ck - o * sk);
    Kb[idx + 1] = f2bf(e * sk + o * ck);
}

// ---------------- GEMM core: Y[m][n] = sum_k A[m][k] * W[n][k], k = 512 ----------------
#define BM 128
#define BN 128
#define BKK 64
#define LDT 72   // pad: row stride 144B breaks b128 16-way conflicts

template <typename OutT>
__device__ __forceinline__ void gemm_body(const unsigned short* __restrict__ A,
                                          const unsigned short* __restrict__ W,
                                          OutT* __restrict__ O, int ldo, int bm, int bn) {
    __shared__ unsigned short As[BM][LDT];
    __shared__ unsigned short Bs[BN][LDT];
    const int tid = threadIdx.x;
    const int wave = tid >> 6, lane = tid & 63;
    const int wm = (wave >> 1) * 64, wn = (wave & 1) * 64;
    const int qd = lane >> 4, ln = lane & 15;
    f32x4 acc[4][4] = {};
    for (int k0 = 0; k0 < D_MODEL; k0 += BKK) {
#pragma unroll
        for (int i = 0; i < 4; i++) {
            int ch = tid + i * 256;
            int r = ch >> 3, c = (ch & 7) * 8;
            *(int4*)&As[r][c] = *(const int4*)&A[(size_t)(bm + r) * D_MODEL + k0 + c];
            *(int4*)&Bs[r][c] = *(const int4*)&W[(size_t)(bn + r) * D_MODEL + k0 + c];
        }
        __syncthreads();
#pragma unroll
        for (int s = 0; s < 2; s++) {
            bf16x8 af[4], bff[4];
#pragma unroll
            for (int t = 0; t < 4; t++) {
                af[t]  = *(const bf16x8*)&As[wm + t * 16 + ln][s * 32 + qd * 8];
                bff[t] = *(const bf16x8*)&Bs[wn + t * 16 + ln][s * 32 + qd * 8];
            }
#pragma unroll
            for (int mi = 0; mi < 4; mi++)
#pragma unroll
                for (int ni = 0; ni < 4; ni++)
                    acc[mi][ni] = __builtin_amdgcn_mfma_f32_16x16x32_bf16(af[mi], bff[ni], acc[mi][ni], 0, 0, 0);
        }
        __syncthreads();
    }
#pragma unroll
    for (int mi = 0; mi < 4; mi++)
#pragma unroll
        for (int ni = 0; ni < 4; ni++)
#pragma unroll
            for (int r = 0; r < 4; r++) {
                int row = bm + wm + mi * 16 + qd * 4 + r;
                int col = bn + wn + ni * 16 + ln;
                if constexpr (__is_same(OutT, float))
                    O[(size_t)row * ldo + col] = acc[mi][ni][r];
                else
                    O[(size_t)row * ldo + col] = f2bf(acc[mi][ni][r]);
            }
}

// Q, K, V^T projections in one launch. z=0: Q, z=1: K (row-major 512), z=2: V^T (ld M)
__global__ __launch_bounds__(256, 2) void gemm_qkv(const unsigned short* __restrict__ xb,
                                                   const unsigned short* __restrict__ Wqb,
                                                   const unsigned short* __restrict__ Wkb,
                                                   const unsigned short* __restrict__ Wvb,
                                                   unsigned short* __restrict__ Qb,
                                                   unsigned short* __restrict__ Kb,
                                                   unsigned short* __restrict__ Vtb, int M) {
    const int z = blockIdx.z;
    if (z == 0)
        gemm_body<unsigned short>(xb, Wqb, Qb, D_MODEL, blockIdx.x * BM, blockIdx.y * BN);
    else if (z == 1)
        gemm_body<unsigned short>(xb, Wkb, Kb, D_MODEL, blockIdx.x * BM, blockIdx.y * BN);
    else  // V^T: Y[dim][token] = sum_k Wv[dim][k] x[token][k]
        gemm_body<unsigned short>(Wvb, xb, Vtb, M, blockIdx.y * BN, blockIdx.x * BM);
}

__global__ __launch_bounds__(256, 2) void gemm_bt_f32(const unsigned short* __restrict__ A,
                                                      const unsigned short* __restrict__ W,
                                                      float* __restrict__ out, int ldo) {
    gemm_body<float>(A, W, out, ldo, blockIdx.x * BM, blockIdx.y * BN);
}

// ---------------- Flash attention v8: q-blocked (A-frag reuse x2) + swizzled LDS ----------
// 256 thr / 4 waves, wave owns 32 q-rows (2 B-frags). Every Ks/Vts A-frag ds_read_b128
// feeds TWO MFMAs -> LDS reads per MFMA 1.125 -> 0.625 (v7's measured LDS floor ~31us/CU
// -> ~17us). No prefetch arrays (R8's scratch trap); sacc kept as two fixed f32x4[8],
// fully unrolled. KT=128, no-max softmax, raw v_exp, Q pre-scaled by SC.
#define QT 128
#define KT 128

__global__ __launch_bounds__(256, 2) void attn_kernel(const unsigned short* __restrict__ Q,
                                                      const unsigned short* __restrict__ K,
                                                      const unsigned short* __restrict__ Vt,
                                                      unsigned short* __restrict__ O, int ldv) {
    __shared__ unsigned short Ks[KT * 64];        // [key][d], 8 chunks/row, swizzled
    __shared__ unsigned short Vts[HEAD_DIM * 128];// [d][key], 16 chunks/row, swizzled
    __shared__ unsigned short Pt[QT * 128];       // Q staging then P[q][key], 16 chunks/row
    const int b = blockIdx.z, h = blockIdx.y, q0 = blockIdx.x * QT;
    const int tid = threadIdx.x, wave = tid >> 6, lane = tid & 63;
    const int qd = lane >> 4, ln = lane & 15;
    const int sw = ln & 7;                         // read-side swizzle key (row & 7 = ln & 7)
    const size_t tbase = ((size_t)b * SEQ) * D_MODEL + h * HEAD_DIM;   // Q/K/O token-major
    const size_t vbase = (size_t)h * HEAD_DIM * ldv + (size_t)b * SEQ; // Vt dim-major

    // stage Q tile (128 rows x 64 dims = chunks 0-7 of each Pt row), swizzled
#pragma unroll
    for (int i = 0; i < 4; i++) {
        int ch = tid + i * 256;                    // 1024 chunks
        int r = ch >> 3, c8 = ch & 7;
        *(int4*)&Pt[r * 128 + ((c8 ^ (r & 7)) * 8)] =
            *(const int4*)&Q[tbase + (size_t)(q0 + r) * D_MODEL + c8 * 8];
    }
    __syncthreads();
    bf16x8 qf[2][2];   // [m][s]: wave owns q rows [wave*32, wave*32+32)
#pragma unroll
    for (int m = 0; m < 2; m++)
#pragma unroll
        for (int s = 0; s < 2; s++)
            qf[m][s] = *(const bf16x8*)&Pt[(wave * 32 + m * 16 + ln) * 128 + (((s * 4 + qd) ^ sw) * 8)];

    f32x4 Oacc0[4] = {}, Oacc1[4] = {};   // O^T tiles per m: row d_local, col q = ln
    float rs0 = 0.f, rs1 = 0.f;           // per-lane partial P sums per m

    for (int kt = 0; kt < SEQ; kt += KT) {
        __syncthreads();   // WAR: prior iter's reads of Ks/Vts done (iter0: qf reads done)
#pragma unroll
        for (int i = 0; i < 4; i++) {
            int ch = tid + i * 256;
            int rk = ch >> 3, c8 = ch & 7;         // Ks: 128 rows x 8 chunks
            *(int4*)&Ks[rk * 64 + ((c8 ^ (rk & 7)) * 8)] =
                *(const int4*)&K[tbase + (size_t)(kt + rk) * D_MODEL + c8 * 8];
            int rv = ch >> 4, c16 = ch & 15;       // Vts: 64 rows x 16 chunks
            *(int4*)&Vts[rv * 128 + ((c16 ^ (rv & 7)) * 8)] =
                *(const int4*)&Vt[vbase + (size_t)rv * ldv + kt + c16 * 8];
        }
        __syncthreads();

        // S^T: each Ks A-frag read once, feeds both q-subtiles
        f32x4 s0[8] = {}, s1[8] = {};
#pragma unroll
        for (int s = 0; s < 2; s++)
#pragma unroll
            for (int g = 0; g < 8; g++) {
                bf16x8 ak = *(const bf16x8*)&Ks[(g * 16 + ln) * 64 + (((s * 4 + qd) ^ sw) * 8)];
                s0[g] = __builtin_amdgcn_mfma_f32_16x16x32_bf16(ak, qf[0][s], s0[g], 0, 0, 0);
                s1[g] = __builtin_amdgcn_mfma_f32_16x16x32_bf16(ak, qf[1][s], s1[g], 0, 0, 0);
            }

        // P = exp2(S) (Q pre-scaled); accumulate rs; pack to Pt[q][key] swizzled
#pragma unroll
        for (int g = 0; g < 8; g++) {
            float p0 = EXP2(s0[g][0]);
            float p1 = EXP2(s0[g][1]);
            float p2 = EXP2(s0[g][2]);
            float p3 = EXP2(s0[g][3]);
            rs0 += (p0 + p1) + (p2 + p3);
            uint2 w = { pkbf(p0, p1), pkbf(p2, p3) };
            *(uint2*)&Pt[(wave * 32 + ln) * 128 + (((g * 2 + (qd >> 1)) ^ sw) * 8) + (qd & 1) * 4] = w;
        }
#pragma unroll
        for (int g = 0; g < 8; g++) {
            float p0 = EXP2(s1[g][0]);
            float p1 = EXP2(s1[g][1]);
            float p2 = EXP2(s1[g][2]);
            float p3 = EXP2(s1[g][3]);
            rs1 += (p0 + p1) + (p2 + p3);
            uint2 w = { pkbf(p0, p1), pkbf(p2, p3) };
            *(uint2*)&Pt[(wave * 32 + 16 + ln) * 128 + (((g * 2 + (qd >> 1)) ^ sw) * 8) + (qd & 1) * 4] = w;
        }
        // Pt rows are wave-private, per-wave DS ops in-order; block compiler reordering only
        asm volatile("" ::: "memory");

        // O^T += V^T · P: each Vts A-frag read once, feeds both q-subtiles
#pragma unroll
        for (int s2 = 0; s2 < 4; s2++) {
            bf16x8 pt0 = *(const bf16x8*)&Pt[(wave * 32 + ln) * 128 + (((s2 * 4 + qd) ^ sw) * 8)];
            bf16x8 pt1 = *(const bf16x8*)&Pt[(wave * 32 + 16 + ln) * 128 + (((s2 * 4 + qd) ^ sw) * 8)];
#pragma unroll
            for (int g2 = 0; g2 < 4; g2++) {
                bf16x8 av = *(const bf16x8*)&Vts[(g2 * 16 + ln) * 128 + (((s2 * 4 + qd) ^ sw) * 8)];
                Oacc0[g2] = __builtin_amdgcn_mfma_f32_16x16x32_bf16(av, pt0, Oacc0[g2], 0, 0, 0);
                Oacc1[g2] = __builtin_amdgcn_mfma_f32_16x16x32_bf16(av, pt1, Oacc1[g2], 0, 0, 0);
            }
        }
    }

    // epilogue per q-subtile: reduce l across quads, normalize, packed b64 stores
    {
        float r = rs0;
        r += __shfl_xor(r, 16, 64);
        r += __shfl_xor(r, 32, 64);
        float inv_l = 1.0f / r;
        const int qrow = q0 + wave * 32 + ln;
#pragma unroll
        for (int g = 0; g < 4; g++) {
            uint2 w = { pkbf(Oacc0[g][0] * inv_l, Oacc0[g][1] * inv_l),
                        pkbf(Oacc0[g][2] * inv_l, Oacc0[g][3] * inv_l) };
            *(uint2*)&O[tbase + (size_t)qrow * D_MODEL + g * 16 + qd * 4] = w;
        }
    }
    {
        float r = rs1;
        r += __shfl_xor(r, 16, 64);
        r += __shfl_xor(r, 32, 64);
        float inv_l = 1.0f / r;
        const int qrow = q0 + wave * 32 + 16 + ln;
#pragma unroll
        for (int g = 0; g < 4; g++) {
            uint2 w = { pkbf(Oacc1[g][0] * inv_l, Oacc1[g][1] * inv_l),
                        pkbf(Oacc1[g][2] * inv_l, Oacc1[g][3] * inv_l) };
            *(uint2*)&O[tbase + (size_t)qrow * D_MODEL + g * 16 + qd * 4] = w;
        }
    }
}

extern "C" void kernel_launch(void* const* d_in, const int* in_sizes, int n_in,
                              void* d_out, int out_size, void* d_ws, size_t ws_size,
                              hipStream_t stream) {
    const float* x    = (const float*)d_in[0];
    const float* qpos = (const float*)d_in[1];
    const float* kpos = (const float*)d_in[2];
    const float* Wq   = (const float*)d_in[3];
    const float* Wk   = (const float*)d_in[5];
    const float* Wv   = (const float*)d_in[7];
    const float* Wo   = (const float*)d_in[9];
    const int M = in_sizes[0] / D_MODEL;   // B*N = 8192
    const int Bn = M / SEQ;                // 4

    char* ws = (char*)d_ws;
    size_t off = 0;
    auto alloc = [&](size_t bytes) { char* p = ws + off; off += (bytes + 255) & ~255ull; return p; };
    unsigned short* xb  = (unsigned short*)alloc((size_t)M * D_MODEL * 2);
    unsigned short* Wqb = (unsigned short*)alloc((size_t)D_MODEL * D_MODEL * 2);
    unsigned short* Wkb = (unsigned short*)alloc((size_t)D_MODEL * D_MODEL * 2);
    unsigned short* Wvb = (unsigned short*)alloc((size_t)D_MODEL * D_MODEL * 2);
    unsigned short* Wob = (unsigned short*)alloc((size_t)D_MODEL * D_MODEL * 2);
    unsigned short* Qb  = (unsigned short*)alloc((size_t)M * D_MODEL * 2);
    unsigned short* Kb  = (unsigned short*)alloc((size_t)M * D_MODEL * 2);
    unsigned short* Vtb = (unsigned short*)alloc((size_t)D_MODEL * M * 2);  // [dim][token]
    unsigned short* Ob  = (unsigned short*)alloc((size_t)M * D_MODEL * 2);

    int n8x = M * D_MODEL / 8;                       // 524288
    int n8w = D_MODEL * D_MODEL / 8;                 // 32768 per weight
    int total = n8x + 4 * n8w;
    cast_all<<<(total + 255) / 256, 256, 0, stream>>>(x, xb, Wq, Wk, Wv, Wo,
                                                      Wqb, Wkb, Wvb, Wob, n8x);

    gemm_qkv<<<dim3(M / BM, D_MODEL / BN, 3), 256, 0, stream>>>(xb, Wqb, Wkb, Wvb, Qb, Kb, Vtb, M);

    rope_kernel<<<M, 256, 0, stream>>>(Qb, Kb, qpos, kpos);

    attn_kernel<<<dim3(SEQ / QT, N_HEADS, Bn), 256, 0, stream>>>(Qb, Kb, Vtb, Ob, M);

    gemm_bt_f32<<<dim3(M / BM, D_MODEL / BN), 256, 0, stream>>>(Ob, Wob, (float*)d_out, D_MODEL);
}

// Round 12
// 191.094 us; speedup vs baseline: 1.0334x; 1.0334x over previous
//
#include <hip/hip_runtime.h>
#include <hip/hip_bf16.h>

typedef __attribute__((ext_vector_type(8))) short bf16x8;
typedef __attribute__((ext_vector_type(8))) unsigned short u16x8;
typedef __attribute__((ext_vector_type(4))) float f32x4;

#define D_MODEL 512
#define HEAD_DIM 64
#define N_HEADS 8
#define SEQ 2048

#if __has_builtin(__builtin_amdgcn_exp2f)
#define EXP2(x) __builtin_amdgcn_exp2f(x)
#else
#define EXP2(x) __expf((x) * 0.69314718f)
#endif

__device__ __forceinline__ unsigned short f2bf(float f) {
    unsigned int u = __float_as_uint(f);
    u += 0x7FFFu + ((u >> 16) & 1u);   // round-to-nearest-even
    return (unsigned short)(u >> 16);
}
__device__ __forceinline__ float bf2f(unsigned short h) {
    return __uint_as_float(((unsigned int)h) << 16);
}
// packed f32x2 -> bf16x2 (v_cvt_pk_bf16_f32 on gfx950)
__device__ __forceinline__ unsigned int pkbf(float a, float b) {
    __hip_bfloat162 h2 = __float22bfloat162_rn(make_float2(a, b));
    unsigned int u;
    __builtin_memcpy(&u, &h2, 4);
    return u;
}

// ---------------- cast fp32 -> bf16: x and 4 weight matrices, one launch ----------------
__global__ void cast_all(const float* __restrict__ x, unsigned short* __restrict__ xb,
                         const float* __restrict__ w0, const float* __restrict__ w1,
                         const float* __restrict__ w2, const float* __restrict__ w3,
                         unsigned short* __restrict__ d0, unsigned short* __restrict__ d1,
                         unsigned short* __restrict__ d2, unsigned short* __restrict__ d3,
                         int n8x) {
    int i = blockIdx.x * blockDim.x + threadIdx.x;
    const float* src; unsigned short* dst; int idx;
    if (i < n8x) { src = x; dst = xb; idx = i; }
    else {
        int j = i - n8x;
        int w = j >> 15; idx = j & 32767;
        switch (w) {
            case 0: src = w0; dst = d0; break;
            case 1: src = w1; dst = d1; break;
            case 2: src = w2; dst = d2; break;
            default: src = w3; dst = d3; break;
        }
        if (w > 3) return;
    }
    const float4* s = (const float4*)src;
    float4 a = s[idx * 2], b = s[idx * 2 + 1];
    u16x8 o;
    o[0] = f2bf(a.x); o[1] = f2bf(a.y); o[2] = f2bf(a.z); o[3] = f2bf(a.w);
    o[4] = f2bf(b.x); o[5] = f2bf(b.y); o[6] = f2bf(b.z); o[7] = f2bf(b.w);
    ((u16x8*)dst)[idx] = o;
}

// ---------------- RoPE on Q,K (bf16, in place); Q additionally scaled by SC ----------------
#define SOFTMAX_SC 0.18033688f   // 1/sqrt(64) * log2(e): attn then uses exp2(S) directly
__global__ void rope_kernel(unsigned short* __restrict__ Qb, unsigned short* __restrict__ Kb,
                            const float* __restrict__ qpos, const float* __restrict__ kpos) {
    int row = blockIdx.x;
    int t = threadIdx.x;
    int h = t >> 5, j = t & 31;
    float pq = qpos[row * 2] + qpos[row * 2 + 1];
    float pk = kpos[row * 2] + kpos[row * 2 + 1];
    float invf = __powf(10000.0f, -(float)j * (1.0f / 16.0f));
    float sq, cq, sk, ck;
    sincosf(pq * invf, &sq, &cq);
    sincosf(pk * invf, &sk, &ck);
    size_t idx = (size_t)row * D_MODEL + h * HEAD_DIM + 2 * j;
    float e = bf2f(Qb[idx]), o = bf2f(Qb[idx + 1]);
    Qb[idx]     = f2bf((e * cq - o * sq) * SOFTMAX_SC);
    Qb[idx + 1] = f2bf((e * sq + o * cq) * SOFTMAX_SC);
    e = bf2f(Kb[idx]); o = bf2f(Kb[idx + 1]);
    Kb[idx]     = f2bf(e * ck - o * sk);
    Kb[idx + 1] = f2bf(e * sk + o * ck);
}

// ---------------- GEMM core: Y[m][n] = sum_k A[m][k] * W[n][k], k = 512 ----------------
#define BM 128
#define BN 128
#define BKK 64
#define LDT 72   // pad: row stride 144B breaks b128 16-way conflicts

template <typename OutT>
__device__ __forceinline__ void gemm_body(const unsigned short* __restrict__ A,
                                          const unsigned short* __restrict__ W,
                                          OutT* __restrict__ O, int ldo, int bm, int bn) {
    __shared__ unsigned short As[BM][LDT];
    __shared__ unsigned short Bs[BN][LDT];
    const int tid = threadIdx.x;
    const int wave = tid >> 6, lane = tid & 63;
    const int wm = (wave >> 1) * 64, wn = (wave & 1) * 64;
    const int qd = lane >> 4, ln = lane & 15;
    f32x4 acc[4][4] = {};
    for (int k0 = 0; k0 < D_MODEL; k0 += BKK) {
#pragma unroll
        for (int i = 0; i < 4; i++) {
            int ch = tid + i * 256;
            int r = ch >> 3, c = (ch & 7) * 8;
            *(int4*)&As[r][c] = *(const int4*)&A[(size_t)(bm + r) * D_MODEL + k0 + c];
            *(int4*)&Bs[r][c] = *(const int4*)&W[(size_t)(bn + r) * D_MODEL + k0 + c];
        }
        __syncthreads();
#pragma unroll
        for (int s = 0; s < 2; s++) {
            bf16x8 af[4], bff[4];
#pragma unroll
            for (int t = 0; t < 4; t++) {
                af[t]  = *(const bf16x8*)&As[wm + t * 16 + ln][s * 32 + qd * 8];
                bff[t] = *(const bf16x8*)&Bs[wn + t * 16 + ln][s * 32 + qd * 8];
            }
#pragma unroll
            for (int mi = 0; mi < 4; mi++)
#pragma unroll
                for (int ni = 0; ni < 4; ni++)
                    acc[mi][ni] = __builtin_amdgcn_mfma_f32_16x16x32_bf16(af[mi], bff[ni], acc[mi][ni], 0, 0, 0);
        }
        __syncthreads();
    }
#pragma unroll
    for (int mi = 0; mi < 4; mi++)
#pragma unroll
        for (int ni = 0; ni < 4; ni++)
#pragma unroll
            for (int r = 0; r < 4; r++) {
                int row = bm + wm + mi * 16 + qd * 4 + r;
                int col = bn + wn + ni * 16 + ln;
                if constexpr (__is_same(OutT, float))
                    O[(size_t)row * ldo + col] = acc[mi][ni][r];
                else
                    O[(size_t)row * ldo + col] = f2bf(acc[mi][ni][r]);
            }
}

// Q, K, V^T projections in one launch. z=0: Q, z=1: K (row-major 512), z=2: V^T (ld M)
__global__ __launch_bounds__(256, 2) void gemm_qkv(const unsigned short* __restrict__ xb,
                                                   const unsigned short* __restrict__ Wqb,
                                                   const unsigned short* __restrict__ Wkb,
                                                   const unsigned short* __restrict__ Wvb,
                                                   unsigned short* __restrict__ Qb,
                                                   unsigned short* __restrict__ Kb,
                                                   unsigned short* __restrict__ Vtb, int M) {
    const int z = blockIdx.z;
    if (z == 0)
        gemm_body<unsigned short>(xb, Wqb, Qb, D_MODEL, blockIdx.x * BM, blockIdx.y * BN);
    else if (z == 1)
        gemm_body<unsigned short>(xb, Wkb, Kb, D_MODEL, blockIdx.x * BM, blockIdx.y * BN);
    else  // V^T: Y[dim][token] = sum_k Wv[dim][k] x[token][k]
        gemm_body<unsigned short>(Wvb, xb, Vtb, M, blockIdx.y * BN, blockIdx.x * BM);
}

__global__ __launch_bounds__(256, 2) void gemm_bt_f32(const unsigned short* __restrict__ A,
                                                      const unsigned short* __restrict__ W,
                                                      float* __restrict__ out, int ldo) {
    gemm_body<float>(A, W, out, ldo, blockIdx.x * BM, blockIdx.y * BN);
}

// ---------------- Flash attention v9: double-buffered K/V, one barrier/iter ----------
// 512 thr / 8 waves x 16 q-rows, KT=64 ping-pong. Iter: write prefetched regs ->
// buf[it&1]; issue next tile's global loads (latency hides under this iter's compute);
// ONE barrier; compute. WAR: reads of buf[j] at iter i-2 are fenced from writes at
// iter i by the iter i-1 barrier. Swizzled LDS (chunk c ^ (row&7)), no-max softmax,
// raw v_exp, Q pre-scaled by SC. LDS 48KB -> 2 blocks/CU, 16 waves/CU.
#define QT 128
#define KT 64

__global__ __launch_bounds__(512, 4) void attn_kernel(const unsigned short* __restrict__ Q,
                                                      const unsigned short* __restrict__ K,
                                                      const unsigned short* __restrict__ Vt,
                                                      unsigned short* __restrict__ O, int ldv) {
    __shared__ unsigned short Ks[2][KT * 64];         // [key][d], 8 chunks/row, swizzled
    __shared__ unsigned short Vts[2][HEAD_DIM * 64];  // [d][key], 8 chunks/row, swizzled
    __shared__ unsigned short Pt[QT * 64];            // Q staging then P[q][key]
    const int b = blockIdx.z, h = blockIdx.y, q0 = blockIdx.x * QT;
    const int tid = threadIdx.x, wave = tid >> 6, lane = tid & 63;
    const int qd = lane >> 4, ln = lane & 15;
    const int sw = ln & 7;                             // read-side swizzle key
    const size_t tbase = ((size_t)b * SEQ) * D_MODEL + h * HEAD_DIM;   // Q/K/O token-major
    const size_t vbase = (size_t)h * HEAD_DIM * ldv + (size_t)b * SEQ; // Vt dim-major

    // staging coords: 512 threads cover 512 chunks (64 rows x 8 chunks) per tile
    const int rk = tid >> 3, ck = tid & 7;
    const int stg = rk * 64 + ((ck ^ (rk & 7)) * 8);   // swizzled LDS offset for staging

    // preload K/V tile 0 into registers
    int4 kr = *(const int4*)&K[tbase + (size_t)rk * D_MODEL + ck * 8];
    int4 vr = *(const int4*)&Vt[vbase + (size_t)rk * ldv + ck * 8];

    // stage Q tile (128 rows x 8 chunks), swizzled
#pragma unroll
    for (int i = 0; i < 2; i++) {
        int ch = tid + i * 512;
        int r = ch >> 3, c8 = ch & 7;
        *(int4*)&Pt[r * 64 + ((c8 ^ (r & 7)) * 8)] =
            *(const int4*)&Q[tbase + (size_t)(q0 + r) * D_MODEL + c8 * 8];
    }
    __syncthreads();
    bf16x8 qf[2];
#pragma unroll
    for (int s = 0; s < 2; s++)
        qf[s] = *(const bf16x8*)&Pt[(wave * 16 + ln) * 64 + (((s * 4 + qd) ^ sw) * 8)];

    f32x4 Oacc[4] = {};            // O^T tiles: row d_local = qd*4+r (tile g), col q = ln
    float rs = 0.f;                // per-lane partial sum of P over this lane's keys

    for (int it = 0; it < SEQ / KT; it++) {
        const int buf = it & 1;
        // write the prefetched tile into this iter's buffer
        *(int4*)&Ks[buf][stg]  = kr;
        *(int4*)&Vts[buf][stg] = vr;
        // prefetch next tile (lands during this iter's compute)
        if (it + 1 < SEQ / KT) {
            int kn = (it + 1) * KT;
            kr = *(const int4*)&K[tbase + (size_t)(kn + rk) * D_MODEL + ck * 8];
            vr = *(const int4*)&Vt[vbase + (size_t)rk * ldv + kn + ck * 8];
        }
        __syncthreads();   // staging visible; also fences iter i-2 reads vs iter i writes

        // S^T: sacc[g][r] = score(key = it*64 + g*16+qd*4+r, q = ln)   [A=K, B=Q]
        f32x4 sacc[4] = {};
#pragma unroll
        for (int s = 0; s < 2; s++)
#pragma unroll
            for (int g = 0; g < 4; g++) {
                bf16x8 ak = *(const bf16x8*)&Ks[buf][(g * 16 + ln) * 64 + (((s * 4 + qd) ^ sw) * 8)];
                sacc[g] = __builtin_amdgcn_mfma_f32_16x16x32_bf16(ak, qf[s], sacc[g], 0, 0, 0);
            }

        // P = exp2(S) (Q pre-scaled); accumulate rs per-lane; pack to Pt[q][key] swizzled
#pragma unroll
        for (int g = 0; g < 4; g++) {
            float p0 = EXP2(sacc[g][0]);
            float p1 = EXP2(sacc[g][1]);
            float p2 = EXP2(sacc[g][2]);
            float p3 = EXP2(sacc[g][3]);
            rs += (p0 + p1) + (p2 + p3);
            uint2 w = { pkbf(p0, p1), pkbf(p2, p3) };
            *(uint2*)&Pt[(wave * 16 + ln) * 64 + (((g * 2 + (qd >> 1)) ^ sw) * 8) + (qd & 1) * 4] = w;
        }
        // Pt rows are wave-private, per-wave DS ops in-order; block compiler reordering only
        asm volatile("" ::: "memory");

        // O^T += V^T · P: A = Vts[d][key], B = Pt[q][key], 64 keys = 2 MFMA K-steps
#pragma unroll
        for (int s2 = 0; s2 < 2; s2++) {
            bf16x8 pt = *(const bf16x8*)&Pt[(wave * 16 + ln) * 64 + (((s2 * 4 + qd) ^ sw) * 8)];
#pragma unroll
            for (int g2 = 0; g2 < 4; g2++) {
                bf16x8 av = *(const bf16x8*)&Vts[buf][(g2 * 16 + ln) * 64 + (((s2 * 4 + qd) ^ sw) * 8)];
                Oacc[g2] = __builtin_amdgcn_mfma_f32_16x16x32_bf16(av, pt, Oacc[g2], 0, 0, 0);
            }
        }
    }

    // l = sum over all keys for q=ln: reduce partial sums across the 4 quads
    rs += __shfl_xor(rs, 16, 64);
    rs += __shfl_xor(rs, 32, 64);
    float inv_l = 1.0f / rs;
    const int qrow = q0 + wave * 16 + ln;
#pragma unroll
    for (int g = 0; g < 4; g++) {
        uint2 w = { pkbf(Oacc[g][0] * inv_l, Oacc[g][1] * inv_l),
                    pkbf(Oacc[g][2] * inv_l, Oacc[g][3] * inv_l) };
        *(uint2*)&O[tbase + (size_t)qrow * D_MODEL + g * 16 + qd * 4] = w;
    }
}

extern "C" void kernel_launch(void* const* d_in, const int* in_sizes, int n_in,
                              void* d_out, int out_size, void* d_ws, size_t ws_size,
                              hipStream_t stream) {
    const float* x    = (const float*)d_in[0];
    const float* qpos = (const float*)d_in[1];
    const float* kpos = (const float*)d_in[2];
    const float* Wq   = (const float*)d_in[3];
    const float* Wk   = (const float*)d_in[5];
    const float* Wv   = (const float*)d_in[7];
    const float* Wo   = (const float*)d_in[9];
    const int M = in_sizes[0] / D_MODEL;   // B*N = 8192
    const int Bn = M / SEQ;                // 4

    char* ws = (char*)d_ws;
    size_t off = 0;
    auto alloc = [&](size_t bytes) { char* p = ws + off; off += (bytes + 255) & ~255ull; return p; };
    unsigned short* xb  = (unsigned short*)alloc((size_t)M * D_MODEL * 2);
    unsigned short* Wqb = (unsigned short*)alloc((size_t)D_MODEL * D_MODEL * 2);
    unsigned short* Wkb = (unsigned short*)alloc((size_t)D_MODEL * D_MODEL * 2);
    unsigned short* Wvb = (unsigned short*)alloc((size_t)D_MODEL * D_MODEL * 2);
    unsigned short* Wob = (unsigned short*)alloc((size_t)D_MODEL * D_MODEL * 2);
    unsigned short* Qb  = (unsigned short*)alloc((size_t)M * D_MODEL * 2);
    unsigned short* Kb  = (unsigned short*)alloc((size_t)M * D_MODEL * 2);
    unsigned short* Vtb = (unsigned short*)alloc((size_t)D_MODEL * M * 2);  // [dim][token]
    unsigned short* Ob  = (unsigned short*)alloc((size_t)M * D_MODEL * 2);

    int n8x = M * D_MODEL / 8;                       // 524288
    int n8w = D_MODEL * D_MODEL / 8;                 // 32768 per weight
    int total = n8x + 4 * n8w;
    cast_all<<<(total + 255) / 256, 256, 0, stream>>>(x, xb, Wq, Wk, Wv, Wo,
                                                      Wqb, Wkb, Wvb, Wob, n8x);

    gemm_qkv<<<dim3(M / BM, D_MODEL / BN, 3), 256, 0, stream>>>(xb, Wqb, Wkb, Wvb, Qb, Kb, Vtb, M);

    rope_kernel<<<M, 256, 0, stream>>>(Qb, Kb, qpos, kpos);

    attn_kernel<<<dim3(SEQ / QT, N_HEADS, Bn), 512, 0, stream>>>(Qb, Kb, Vtb, Ob, M);

    gemm_bt_f32<<<dim3(M / BM, D_MODEL / BN), 256, 0, stream>>>(Ob, Wob, (float*)d_out, D_MODEL);
}